// Round 4
// baseline (269.989 us; speedup 1.0000x reference)
//
#include <hip/hip_runtime.h>
#include <math.h>

#define BLOCK 256
#define GRID  2048          // 8192 dual-tiles / 2048 = 4 iters per block

typedef _Float16 half8 __attribute__((ext_vector_type(8)));
typedef float    f32x4 __attribute__((ext_vector_type(4)));

// Output-column permutation: producer layer writes logical out-feat
// phi(nt, i) into MFMA out-slot (nt, i). Then lane (m,q)'s C quads
// (acc[nt][r] = feat phi(nt, q*4+r)) packed pairwise give exactly the
// consumer B-frag halves (feats kt*32 + q*8 + j, j=0..7) with ZERO data
// movement: activations chain lane-locally through registers.
__device__ __forceinline__ int phi(int nt, int m) {
    return ((nt >> 1) << 5) + ((m >> 2) << 3) + ((nt & 1) << 2) + (m & 3);
}

// A-operand weight fragment: lane (m,q) holds A[i=m][k=q*8+j] = w[k][nsrc].
// w row-major [Kreal, N0]; out-of-range k or !valid -> 0.
__device__ __forceinline__ half8 bfragW(const float* __restrict__ w, int N0,
                                        int nsrc, int k0, int Kreal, bool valid) {
    half8 r;
    #pragma unroll
    for (int j = 0; j < 8; j++) {
        int k = k0 + j;
        float v = (valid && k < Kreal) ? w[k * N0 + nsrc] : 0.f;
        r[j] = (_Float16)v;
    }
    return r;
}

__device__ __forceinline__ half8 packrelu(f32x4 a, f32x4 b) {
    half8 h;
    #pragma unroll
    for (int r = 0; r < 4; r++) {
        h[r]     = (_Float16)fmaxf(a[r], 0.f);
        h[4 + r] = (_Float16)fmaxf(b[r], 0.f);
    }
    return h;
}

__device__ __forceinline__ half8 packraw(f32x4 a, f32x4 b) {
    half8 h;
    #pragma unroll
    for (int r = 0; r < 4; r++) {
        h[r]     = (_Float16)a[r];
        h[4 + r] = (_Float16)b[r];
    }
    return h;
}

__device__ __forceinline__ void sh16(float x, float y, float z, float* e) {
    float xx = x * x, yy = y * y, zz = z * z;
    float xy = x * y, yz = y * z, xz = x * z;
    e[0]  = 0.28209479177387814f;
    e[1]  = -0.48860251190291987f * y;
    e[2]  = 0.48860251190291987f * z;
    e[3]  = -0.48860251190291987f * x;
    e[4]  = 1.0925484305920792f * xy;
    e[5]  = -1.0925484305920792f * yz;
    e[6]  = 0.94617469575756f * zz - 0.31539156525252005f;
    e[7]  = -1.0925484305920792f * xz;
    e[8]  = 0.5462742152960396f * (xx - yy);
    e[9]  = 0.5900435899266435f * y * (3.0f * xx - yy);
    e[10] = 2.890611442640554f * xy * z;
    e[11] = 0.4570457994644657f * y * (4.0f * zz - xx - yy);
    e[12] = 0.3731763325901154f * z * (2.0f * zz - 3.0f * xx - 3.0f * yy);
    e[13] = 0.4570457994644657f * x * (4.0f * zz - xx - yy);
    e[14] = 1.445305721320277f * z * (xx - yy);
    e[15] = 0.5900435899266435f * x * (xx - 3.0f * yy);
}

#define MFMA(A, B, C) __builtin_amdgcn_mfma_f32_16x16x32_f16((A), (B), (C), 0, 0, 0)
#define SBAR() __builtin_amdgcn_sched_barrier(0)

// ---- LDS weight-fragment table: 40 frags x 64 lanes x 16B = 40 KiB ----
// Dual point-chain per wave: each frag read feeds 2 MFMAs (A,B chains).
// ROUND-4 CHANGE: __launch_bounds__(256,2). Evidence from rounds 0-3:
// scratch-spill volume tracks the launch_bounds register cap, not the
// live set (bounds4/128regs -> 137MB spill even with a ~90-reg live set;
// bounds3/170 -> 92MB; bounds2/256 -> 40MB with a BIGGER live set).
// The scheduler's cross-iteration pipelining inflates demand ~50 regs;
// giving it a 256-reg ceiling lets it pipeline WITHOUT spilling. The
// bound is a cap, not a target: if allocation lands <=170 we still get
// 3 blocks/CU at runtime.
#define NFRAG  40
#define F_SIG0 0    // 4  frags  [nt]
#define F_COL0 4    // 8  frags  [nt*2+kt]
#define F_VIS0 12   // 8  frags  [nt*2+kt]
#define F_SIG1 20   // 4  frags  [nt*2+kt], nt<2
#define F_VIS1 24   // 2  frags  [kt]
#define F_COL1 26   // 12 frags  [nt*3+kt]
#define F_COL2 38   // 2  frags  [kt]

__global__ __launch_bounds__(BLOCK, 2) void nerf_dual2(
    const float* __restrict__ x_feat,
    const float* __restrict__ dvec,
    const float* __restrict__ lvec,
    const float* __restrict__ w_sig0,   // [32,64]
    const float* __restrict__ w_sig1,   // [64,16]
    const float* __restrict__ w_col0,   // [64,64]
    const float* __restrict__ w_col1,   // [79,64]
    const float* __restrict__ w_col2,   // [64,3]
    const float* __restrict__ w_vis0,   // [48,64]
    const float* __restrict__ w_vis1,   // [64,1]
    float* __restrict__ out, int n)
{
    const int tid  = threadIdx.x;
    const int wv   = tid >> 6;
    const int lane = tid & 63;
    const int m    = lane & 15;
    const int q    = lane >> 4;

    __shared__ half8 WL[NFRAG * 64];

    // ---------- one-time staging: each wave fills a subset of frags ----------
    if (wv == 0) {
        #pragma unroll
        for (int nt = 0; nt < 4; nt++)
            WL[(F_SIG0 + nt) * 64 + lane] =
                bfragW(w_sig0, 64, phi(nt, m), q * 8, 32, true);
        // sig1 -> geo, widened to 32 out-cols with zero pads (col1 kt=2 layout)
        #pragma unroll
        for (int nt = 0; nt < 2; nt++)
            #pragma unroll
            for (int kt = 0; kt < 2; kt++) {
                int g = ((m >> 2) << 3) + ((nt & 1) << 2) + (m & 3);
                bool valid = ((m >> 2) < 2) && (g < 15);
                WL[(F_SIG1 + nt * 2 + kt) * 64 + lane] =
                    bfragW(w_sig1, 16, g + 1, kt * 32 + q * 8, 64, valid);
            }
        #pragma unroll
        for (int kt = 0; kt < 2; kt++)
            WL[(F_VIS1 + kt) * 64 + lane] =
                bfragW(w_vis1, 1, 0, kt * 32 + q * 8, 64, m == 0);
    } else if (wv == 1) {
        #pragma unroll
        for (int nt = 0; nt < 4; nt++)
            #pragma unroll
            for (int kt = 0; kt < 2; kt++)
                WL[(F_COL0 + nt * 2 + kt) * 64 + lane] =
                    bfragW(w_col0, 64, phi(nt, m), kt * 32 + q * 8, 64, true);
        #pragma unroll
        for (int kt = 0; kt < 2; kt++)
            WL[(F_COL2 + kt) * 64 + lane] =
                bfragW(w_col2, 3, m, kt * 32 + q * 8, 64, m < 3);
    } else if (wv == 2) {
        #pragma unroll
        for (int nt = 0; nt < 4; nt++)
            #pragma unroll
            for (int kt = 0; kt < 2; kt++)   // k rows 48..63 zero (denc unused)
                WL[(F_VIS0 + nt * 2 + kt) * 64 + lane] =
                    bfragW(w_vis0, 64, phi(nt, m), kt * 32 + q * 8, 48, true);
    } else {
        #pragma unroll
        for (int nt = 0; nt < 4; nt++)
            #pragma unroll
            for (int kt = 0; kt < 3; kt++)   // K=79; rows 79..95 zero
                WL[(F_COL1 + nt * 3 + kt) * 64 + lane] =
                    bfragW(w_col1, 64, phi(nt, m), kt * 32 + q * 8, 79, true);
    }
    __syncthreads();
    // Weights are read-only from here: NO barriers in the main loop.

    int wl = lane;   // LDS element offset; made loop-opaque below to stop
                     // LICM from hoisting 40 frag reads back into registers
                     // (160 regs of weights would re-blow the budget).
    #define LW(f) WL[wl + (f) * 64]

    const f32x4 z = {0.f, 0.f, 0.f, 0.f};
    const int ntiles = n >> 7;           // 128 points per block, 32 per wave
    for (int t = blockIdx.x; t < ntiles; t += GRID) {
        asm volatile("" : "+v"(wl));     // block LICM/CSE of LW() across iters

        const int pt0 = (t << 7) + wv * 32 + m;   // chain A point
        const int pt1 = pt0 + 16;                 // chain B point

        // ---- inputs, chain A ----
        half8 fA0, fA1;
        {
            const float4* xa = (const float4*)(x_feat + (size_t)pt0 * 32 + q * 8);
            float4 v0 = xa[0], v1 = xa[1];
            fA0[0] = (_Float16)v0.x; fA0[1] = (_Float16)v0.y;
            fA0[2] = (_Float16)v0.z; fA0[3] = (_Float16)v0.w;
            fA0[4] = (_Float16)v1.x; fA0[5] = (_Float16)v1.y;
            fA0[6] = (_Float16)v1.z; fA0[7] = (_Float16)v1.w;
            const float* va = (q < 2 ? lvec : dvec) + (size_t)pt0 * 3;
            float e[16];
            sh16(va[0], va[1], va[2], e);
            #pragma unroll
            for (int u = 0; u < 8; u++) {
                float s = (q & 1) ? e[8 + u] : e[u];   // select in f32
                fA1[u] = (_Float16)s;
            }
        }
        // ---- inputs, chain B (e[] reused: only one SH array live) ----
        half8 fB0, fB1;
        {
            const float4* xb = (const float4*)(x_feat + (size_t)pt1 * 32 + q * 8);
            float4 u0 = xb[0], u1 = xb[1];
            fB0[0] = (_Float16)u0.x; fB0[1] = (_Float16)u0.y;
            fB0[2] = (_Float16)u0.z; fB0[3] = (_Float16)u0.w;
            fB0[4] = (_Float16)u1.x; fB0[5] = (_Float16)u1.y;
            fB0[6] = (_Float16)u1.z; fB0[7] = (_Float16)u1.w;
            const float* vb = (q < 2 ? lvec : dvec) + (size_t)pt1 * 3;
            float e[16];
            sh16(vb[0], vb[1], vb[2], e);
            #pragma unroll
            for (int u = 0; u < 8; u++) {
                float s = (q & 1) ? e[8 + u] : e[u];
                fB1[u] = (_Float16)s;
            }
        }
        SBAR();

        half8 w;
        f32x4 aA, aB, bA, bB;

        // ---- sig0: h = relu(x @ w_sig0), K=32 ----
        w = LW(F_SIG0 + 0); aA = MFMA(w, fA0, z); aB = MFMA(w, fB0, z);
        w = LW(F_SIG0 + 1); bA = MFMA(w, fA0, z); bB = MFMA(w, fB0, z);
        half8 hK0a = packrelu(aA, bA), hK0b = packrelu(aB, bB);
        w = LW(F_SIG0 + 2); aA = MFMA(w, fA0, z); aB = MFMA(w, fB0, z);
        w = LW(F_SIG0 + 3); bA = MFMA(w, fA0, z); bB = MFMA(w, fB0, z);
        half8 hK1a = packrelu(aA, bA), hK1b = packrelu(aB, bB);
        SBAR();

        // ---- sig1 immediately (frees hK*): geo = h @ w_sig1, no relu ----
        aA = z; aB = z; bA = z; bB = z;
        w = LW(F_SIG1 + 0); aA = MFMA(w, hK0a, aA); aB = MFMA(w, hK0b, aB);
        w = LW(F_SIG1 + 1); aA = MFMA(w, hK1a, aA); aB = MFMA(w, hK1b, aB);
        w = LW(F_SIG1 + 2); bA = MFMA(w, hK0a, bA); bB = MFMA(w, hK0b, bB);
        w = LW(F_SIG1 + 3); bA = MFMA(w, hK1a, bA); bB = MFMA(w, hK1b, bB);
        half8 gA = packraw(aA, bA), gB = packraw(aB, bB);
        SBAR();

        // ---- col0: hc = relu([x|lenc|denc] @ w_col0), K=64 ----
        aA = z; aB = z; bA = z; bB = z;
        w = LW(F_COL0 + 0); aA = MFMA(w, fA0, aA); aB = MFMA(w, fB0, aB);
        w = LW(F_COL0 + 1); aA = MFMA(w, fA1, aA); aB = MFMA(w, fB1, aB);
        w = LW(F_COL0 + 2); bA = MFMA(w, fA0, bA); bB = MFMA(w, fB0, bB);
        w = LW(F_COL0 + 3); bA = MFMA(w, fA1, bA); bB = MFMA(w, fB1, bB);
        half8 cK0a = packrelu(aA, bA), cK0b = packrelu(aB, bB);
        aA = z; aB = z; bA = z; bB = z;
        w = LW(F_COL0 + 4); aA = MFMA(w, fA0, aA); aB = MFMA(w, fB0, aB);
        w = LW(F_COL0 + 5); aA = MFMA(w, fA1, aA); aB = MFMA(w, fB1, aB);
        w = LW(F_COL0 + 6); bA = MFMA(w, fA0, bA); bB = MFMA(w, fB0, bB);
        w = LW(F_COL0 + 7); bA = MFMA(w, fA1, bA); bB = MFMA(w, fB1, bB);
        half8 cK1a = packrelu(aA, bA), cK1b = packrelu(aB, bB);
        SBAR();

        // ---- vis0: hv = relu([x|lenc|0] @ w_vis0), K=64 (rows 48+ zero) ----
        aA = z; aB = z; bA = z; bB = z;
        w = LW(F_VIS0 + 0); aA = MFMA(w, fA0, aA); aB = MFMA(w, fB0, aB);
        w = LW(F_VIS0 + 1); aA = MFMA(w, fA1, aA); aB = MFMA(w, fB1, aB);
        w = LW(F_VIS0 + 2); bA = MFMA(w, fA0, bA); bB = MFMA(w, fB0, bB);
        w = LW(F_VIS0 + 3); bA = MFMA(w, fA1, bA); bB = MFMA(w, fB1, bB);
        half8 vK0a = packrelu(aA, bA), vK0b = packrelu(aB, bB);
        aA = z; aB = z; bA = z; bB = z;
        w = LW(F_VIS0 + 4); aA = MFMA(w, fA0, aA); aB = MFMA(w, fB0, aB);
        w = LW(F_VIS0 + 5); aA = MFMA(w, fA1, aA); aB = MFMA(w, fB1, aB);
        w = LW(F_VIS0 + 6); bA = MFMA(w, fA0, bA); bB = MFMA(w, fB0, bB);
        w = LW(F_VIS0 + 7); bA = MFMA(w, fA1, bA); bB = MFMA(w, fB1, bB);
        half8 vK1a = packrelu(aA, bA), vK1b = packrelu(aB, bB);

        // ---- vis1 + sigmoid immediately (frees vK*, and fI* after this) ----
        f32x4 va = z, vb = z;
        w = LW(F_VIS1 + 0); va = MFMA(w, vK0a, va); vb = MFMA(w, vK0b, vb);
        w = LW(F_VIS1 + 1); va = MFMA(w, vK1a, va); vb = MFMA(w, vK1b, vb);
        float visA = 1.f / (1.f + expf(-va[0]));
        float visB = 1.f / (1.f + expf(-vb[0]));
        SBAR();

        // ---- col1: h2 = relu([hc|geo] @ w_col1), K=96 padded ----
        aA = z; aB = z; bA = z; bB = z;
        w = LW(F_COL1 + 0);  aA = MFMA(w, cK0a, aA); aB = MFMA(w, cK0b, aB);
        w = LW(F_COL1 + 1);  aA = MFMA(w, cK1a, aA); aB = MFMA(w, cK1b, aB);
        w = LW(F_COL1 + 2);  aA = MFMA(w, gA,   aA); aB = MFMA(w, gB,   aB);
        w = LW(F_COL1 + 3);  bA = MFMA(w, cK0a, bA); bB = MFMA(w, cK0b, bB);
        w = LW(F_COL1 + 4);  bA = MFMA(w, cK1a, bA); bB = MFMA(w, cK1b, bB);
        w = LW(F_COL1 + 5);  bA = MFMA(w, gA,   bA); bB = MFMA(w, gB,   bB);
        half8 h2K0a = packrelu(aA, bA), h2K0b = packrelu(aB, bB);
        aA = z; aB = z; bA = z; bB = z;
        w = LW(F_COL1 + 6);  aA = MFMA(w, cK0a, aA); aB = MFMA(w, cK0b, aB);
        w = LW(F_COL1 + 7);  aA = MFMA(w, cK1a, aA); aB = MFMA(w, cK1b, aB);
        w = LW(F_COL1 + 8);  aA = MFMA(w, gA,   aA); aB = MFMA(w, gB,   aB);
        w = LW(F_COL1 + 9);  bA = MFMA(w, cK0a, bA); bB = MFMA(w, cK0b, bB);
        w = LW(F_COL1 + 10); bA = MFMA(w, cK1a, bA); bB = MFMA(w, cK1b, bB);
        w = LW(F_COL1 + 11); bA = MFMA(w, gA,   bA); bB = MFMA(w, gB,   bB);
        half8 h2K1a = packrelu(aA, bA), h2K1b = packrelu(aB, bB);
        SBAR();

        // ---- col2: color = relu(h2 @ w_col2) * vis; rows 0..2 at q==0 ----
        f32x4 ca = z, cb = z;
        w = LW(F_COL2 + 0); ca = MFMA(w, h2K0a, ca); cb = MFMA(w, h2K0b, cb);
        w = LW(F_COL2 + 1); ca = MFMA(w, h2K1a, ca); cb = MFMA(w, h2K1b, cb);
        if (q == 0) {
            float* oa = out + (size_t)pt0 * 3;
            oa[0] = fmaxf(ca[0], 0.f) * visA;
            oa[1] = fmaxf(ca[1], 0.f) * visA;
            oa[2] = fmaxf(ca[2], 0.f) * visA;
            float* ob = out + (size_t)pt1 * 3;
            ob[0] = fmaxf(cb[0], 0.f) * visB;
            ob[1] = fmaxf(cb[1], 0.f) * visB;
            ob[2] = fmaxf(cb[2], 0.f) * visB;
        }
    }
    #undef LW
}

extern "C" void kernel_launch(void* const* d_in, const int* in_sizes, int n_in,
                              void* d_out, int out_size, void* d_ws, size_t ws_size,
                              hipStream_t stream) {
    const float* x_feat = (const float*)d_in[0];
    const float* dvec   = (const float*)d_in[1];
    const float* lvec   = (const float*)d_in[2];
    const float* w_sig0 = (const float*)d_in[3];
    const float* w_sig1 = (const float*)d_in[4];
    const float* w_col0 = (const float*)d_in[5];
    const float* w_col1 = (const float*)d_in[6];
    const float* w_col2 = (const float*)d_in[7];
    const float* w_vis0 = (const float*)d_in[8];
    const float* w_vis1 = (const float*)d_in[9];
    float* out = (float*)d_out;

    const int n = in_sizes[0] / 32;   // N points (1048576: multiple of 128)
    nerf_dual2<<<GRID, BLOCK, 0, stream>>>(x_feat, dvec, lvec,
                                           w_sig0, w_sig1, w_col0, w_col1,
                                           w_col2, w_vis0, w_vis1, out, n);
}

// Round 5
// 239.366 us; speedup vs baseline: 1.1279x; 1.1279x over previous
//
#include <hip/hip_runtime.h>
#include <math.h>

#define BLOCK 256
#define GRID  2048          // 8192 dual-tiles / 2048 = 4 iters per block

typedef _Float16 half8 __attribute__((ext_vector_type(8)));
typedef float    f32x4 __attribute__((ext_vector_type(4)));

// Output-column permutation: producer layer writes logical out-feat
// phi(nt, i) into MFMA out-slot (nt, i). Then lane (m,q)'s C quads
// (acc[nt][r] = feat phi(nt, q*4+r)) packed pairwise give exactly the
// consumer B-frag halves (feats kt*32 + q*8 + j, j=0..7) with ZERO data
// movement: activations chain lane-locally through registers.
__device__ __forceinline__ int phi(int nt, int m) {
    return ((nt >> 1) << 5) + ((m >> 2) << 3) + ((nt & 1) << 2) + (m & 3);
}

// A-operand weight fragment: lane (m,q) holds A[i=m][k=q*8+j] = w[k][nsrc].
// w row-major [Kreal, N0]; out-of-range k or !valid -> 0.
__device__ __forceinline__ half8 bfragW(const float* __restrict__ w, int N0,
                                        int nsrc, int k0, int Kreal, bool valid) {
    half8 r;
    #pragma unroll
    for (int j = 0; j < 8; j++) {
        int k = k0 + j;
        float v = (valid && k < Kreal) ? w[k * N0 + nsrc] : 0.f;
        r[j] = (_Float16)v;
    }
    return r;
}

__device__ __forceinline__ half8 packrelu(f32x4 a, f32x4 b) {
    half8 h;
    #pragma unroll
    for (int r = 0; r < 4; r++) {
        h[r]     = (_Float16)fmaxf(a[r], 0.f);
        h[4 + r] = (_Float16)fmaxf(b[r], 0.f);
    }
    return h;
}

__device__ __forceinline__ half8 packraw(f32x4 a, f32x4 b) {
    half8 h;
    #pragma unroll
    for (int r = 0; r < 4; r++) {
        h[r]     = (_Float16)a[r];
        h[4 + r] = (_Float16)b[r];
    }
    return h;
}

// SH degree-4 (16 comps) -> one half8 fragment, ALL NAMED SCALARS.
// Round-4 lesson: the old float e[16] array (pointer-passed into sh16,
// then 2-element selects) generated persistent scratch traffic (~95MB of
// non-output HBM writes at EVERY launch_bounds setting). No addressable
// object -> nothing the allocator can demote to scratch.
// hi=false -> comps 0..7, hi=true -> comps 8..15.
__device__ __forceinline__ half8 shfrag(float x, float y, float z, bool hi) {
    float xx = x * x, yy = y * y, zz = z * z;
    float xy = x * y, yz = y * z, xz = x * z;
    float e0  = 0.28209479177387814f;
    float e1  = -0.48860251190291987f * y;
    float e2  = 0.48860251190291987f * z;
    float e3  = -0.48860251190291987f * x;
    float e4  = 1.0925484305920792f * xy;
    float e5  = -1.0925484305920792f * yz;
    float e6  = 0.94617469575756f * zz - 0.31539156525252005f;
    float e7  = -1.0925484305920792f * xz;
    float e8  = 0.5462742152960396f * (xx - yy);
    float e9  = 0.5900435899266435f * y * (3.0f * xx - yy);
    float e10 = 2.890611442640554f * xy * z;
    float e11 = 0.4570457994644657f * y * (4.0f * zz - xx - yy);
    float e12 = 0.3731763325901154f * z * (2.0f * zz - 3.0f * xx - 3.0f * yy);
    float e13 = 0.4570457994644657f * x * (4.0f * zz - xx - yy);
    float e14 = 1.445305721320277f * z * (xx - yy);
    float e15 = 0.5900435899266435f * x * (xx - 3.0f * yy);
    half8 r;
    r[0] = (_Float16)(hi ? e8  : e0);
    r[1] = (_Float16)(hi ? e9  : e1);
    r[2] = (_Float16)(hi ? e10 : e2);
    r[3] = (_Float16)(hi ? e11 : e3);
    r[4] = (_Float16)(hi ? e12 : e4);
    r[5] = (_Float16)(hi ? e13 : e5);
    r[6] = (_Float16)(hi ? e14 : e6);
    r[7] = (_Float16)(hi ? e15 : e7);
    return r;
}

__device__ __forceinline__ half8 cvt8(float4 v0, float4 v1) {
    half8 f;
    f[0] = (_Float16)v0.x; f[1] = (_Float16)v0.y;
    f[2] = (_Float16)v0.z; f[3] = (_Float16)v0.w;
    f[4] = (_Float16)v1.x; f[5] = (_Float16)v1.y;
    f[6] = (_Float16)v1.z; f[7] = (_Float16)v1.w;
    return f;
}

#define MFMA(A, B, C) __builtin_amdgcn_mfma_f32_16x16x32_f16((A), (B), (C), 0, 0, 0)
#define SBAR() __builtin_amdgcn_sched_barrier(0)

// ---- LDS weight-fragment table: 40 frags x 64 lanes x 16B = 40 KiB ----
// Dual point-chain per wave: each frag read feeds 2 MFMAs (A,B chains).
// Pressure control: pairwise accumulators, sig1/vis1 right after their
// producers, sched_barrier(0) at layer boundaries. Inputs for iteration
// t+1 are prefetched into raw registers (~22 VGPRs) while iteration t
// computes, hiding HBM latency under the MFMA body.
#define NFRAG  40
#define F_SIG0 0    // 4  frags  [nt]
#define F_COL0 4    // 8  frags  [nt*2+kt]
#define F_VIS0 12   // 8  frags  [nt*2+kt]
#define F_SIG1 20   // 4  frags  [nt*2+kt], nt<2
#define F_VIS1 24   // 2  frags  [kt]
#define F_COL1 26   // 12 frags  [nt*3+kt]
#define F_COL2 38   // 2  frags  [kt]

__global__ __launch_bounds__(BLOCK, 3) void nerf_pf(
    const float* __restrict__ x_feat,
    const float* __restrict__ dvec,
    const float* __restrict__ lvec,
    const float* __restrict__ w_sig0,   // [32,64]
    const float* __restrict__ w_sig1,   // [64,16]
    const float* __restrict__ w_col0,   // [64,64]
    const float* __restrict__ w_col1,   // [79,64]
    const float* __restrict__ w_col2,   // [64,3]
    const float* __restrict__ w_vis0,   // [48,64]
    const float* __restrict__ w_vis1,   // [64,1]
    float* __restrict__ out, int n)
{
    const int tid  = threadIdx.x;
    const int wv   = tid >> 6;
    const int lane = tid & 63;
    const int m    = lane & 15;
    const int q    = lane >> 4;

    __shared__ half8 WL[NFRAG * 64];

    const float* dl = (q < 2) ? lvec : dvec;   // SH source for this lane
    const int ntiles = n >> 7;                 // 128 pts per block, 32 per wave

    // ---- issue iter-0 input loads FIRST (in flight during staging) ----
    float4 rxa0, rxa1, rxb0, rxb1;
    float rvax, rvay, rvaz, rvbx, rvby, rvbz;
    {
        const int t0  = blockIdx.x;
        const int pt0 = (t0 << 7) + wv * 32 + m;
        const int pt1 = pt0 + 16;
        const float4* xa = (const float4*)(x_feat + (size_t)pt0 * 32 + q * 8);
        rxa0 = xa[0]; rxa1 = xa[1];
        const float4* xb = (const float4*)(x_feat + (size_t)pt1 * 32 + q * 8);
        rxb0 = xb[0]; rxb1 = xb[1];
        const float* va = dl + (size_t)pt0 * 3;
        rvax = va[0]; rvay = va[1]; rvaz = va[2];
        const float* vb = dl + (size_t)pt1 * 3;
        rvbx = vb[0]; rvby = vb[1]; rvbz = vb[2];
    }

    // ---------- one-time staging: each wave fills a subset of frags ----------
    if (wv == 0) {
        #pragma unroll
        for (int nt = 0; nt < 4; nt++)
            WL[(F_SIG0 + nt) * 64 + lane] =
                bfragW(w_sig0, 64, phi(nt, m), q * 8, 32, true);
        // sig1 -> geo, widened to 32 out-cols with zero pads (col1 kt=2 layout)
        #pragma unroll
        for (int nt = 0; nt < 2; nt++)
            #pragma unroll
            for (int kt = 0; kt < 2; kt++) {
                int g = ((m >> 2) << 3) + ((nt & 1) << 2) + (m & 3);
                bool valid = ((m >> 2) < 2) && (g < 15);
                WL[(F_SIG1 + nt * 2 + kt) * 64 + lane] =
                    bfragW(w_sig1, 16, g + 1, kt * 32 + q * 8, 64, valid);
            }
        #pragma unroll
        for (int kt = 0; kt < 2; kt++)
            WL[(F_VIS1 + kt) * 64 + lane] =
                bfragW(w_vis1, 1, 0, kt * 32 + q * 8, 64, m == 0);
    } else if (wv == 1) {
        #pragma unroll
        for (int nt = 0; nt < 4; nt++)
            #pragma unroll
            for (int kt = 0; kt < 2; kt++)
                WL[(F_COL0 + nt * 2 + kt) * 64 + lane] =
                    bfragW(w_col0, 64, phi(nt, m), kt * 32 + q * 8, 64, true);
        #pragma unroll
        for (int kt = 0; kt < 2; kt++)
            WL[(F_COL2 + kt) * 64 + lane] =
                bfragW(w_col2, 3, m, kt * 32 + q * 8, 64, m < 3);
    } else if (wv == 2) {
        #pragma unroll
        for (int nt = 0; nt < 4; nt++)
            #pragma unroll
            for (int kt = 0; kt < 2; kt++)   // k rows 48..63 zero (denc unused)
                WL[(F_VIS0 + nt * 2 + kt) * 64 + lane] =
                    bfragW(w_vis0, 64, phi(nt, m), kt * 32 + q * 8, 48, true);
    } else {
        #pragma unroll
        for (int nt = 0; nt < 4; nt++)
            #pragma unroll
            for (int kt = 0; kt < 3; kt++)   // K=79; rows 79..95 zero
                WL[(F_COL1 + nt * 3 + kt) * 64 + lane] =
                    bfragW(w_col1, 64, phi(nt, m), kt * 32 + q * 8, 79, true);
    }
    __syncthreads();
    // Weights are read-only from here: NO barriers in the main loop.

    int wl = lane;   // LDS element offset; made loop-opaque below to stop
                     // LICM from hoisting 40 frag reads back into registers
                     // (160 regs of weights would re-blow the budget).
    #define LW(f) WL[wl + (f) * 64]

    const f32x4 z = {0.f, 0.f, 0.f, 0.f};
    for (int t = blockIdx.x; t < ntiles; t += GRID) {
        asm volatile("" : "+v"(wl));     // block LICM/CSE of LW() across iters

        const int pt0 = (t << 7) + wv * 32 + m;   // chain A point
        const int pt1 = pt0 + 16;                 // chain B point

        // ---- convert current raw inputs -> frags (raws dead after this) ----
        half8 fA0 = cvt8(rxa0, rxa1);
        half8 fB0 = cvt8(rxb0, rxb1);
        half8 fA1 = shfrag(rvax, rvay, rvaz, (q & 1) != 0);
        half8 fB1 = shfrag(rvbx, rvby, rvbz, (q & 1) != 0);

        // ---- issue prefetch for iter t+GRID (latency hides under body) ----
        {
            int tn = t + GRID;
            int tp = (tn < ntiles) ? tn : t;      // uniform; safe addr on tail
            const int qt0 = (tp << 7) + wv * 32 + m;
            const int qt1 = qt0 + 16;
            const float4* xa = (const float4*)(x_feat + (size_t)qt0 * 32 + q * 8);
            rxa0 = xa[0]; rxa1 = xa[1];
            const float4* xb = (const float4*)(x_feat + (size_t)qt1 * 32 + q * 8);
            rxb0 = xb[0]; rxb1 = xb[1];
            const float* va = dl + (size_t)qt0 * 3;
            rvax = va[0]; rvay = va[1]; rvaz = va[2];
            const float* vb = dl + (size_t)qt1 * 3;
            rvbx = vb[0]; rvby = vb[1]; rvbz = vb[2];
        }

        half8 w;
        f32x4 aA, aB, bA, bB;

        // ---- sig0: h = relu(x @ w_sig0), K=32 (no SBAR above: its ds_reads
        //      may overlap input conversion / prefetch issue) ----
        w = LW(F_SIG0 + 0); aA = MFMA(w, fA0, z); aB = MFMA(w, fB0, z);
        w = LW(F_SIG0 + 1); bA = MFMA(w, fA0, z); bB = MFMA(w, fB0, z);
        half8 hK0a = packrelu(aA, bA), hK0b = packrelu(aB, bB);
        w = LW(F_SIG0 + 2); aA = MFMA(w, fA0, z); aB = MFMA(w, fB0, z);
        w = LW(F_SIG0 + 3); bA = MFMA(w, fA0, z); bB = MFMA(w, fB0, z);
        half8 hK1a = packrelu(aA, bA), hK1b = packrelu(aB, bB);
        SBAR();

        // ---- sig1 immediately (frees hK*): geo = h @ w_sig1, no relu ----
        w = LW(F_SIG1 + 0); aA = MFMA(w, hK0a, z);  aB = MFMA(w, hK0b, z);
        w = LW(F_SIG1 + 1); aA = MFMA(w, hK1a, aA); aB = MFMA(w, hK1b, aB);
        w = LW(F_SIG1 + 2); bA = MFMA(w, hK0a, z);  bB = MFMA(w, hK0b, z);
        w = LW(F_SIG1 + 3); bA = MFMA(w, hK1a, bA); bB = MFMA(w, hK1b, bB);
        half8 gA = packraw(aA, bA), gB = packraw(aB, bB);
        SBAR();

        // ---- col0: hc = relu([x|lenc|denc] @ w_col0), K=64 ----
        w = LW(F_COL0 + 0); aA = MFMA(w, fA0, z);  aB = MFMA(w, fB0, z);
        w = LW(F_COL0 + 1); aA = MFMA(w, fA1, aA); aB = MFMA(w, fB1, aB);
        w = LW(F_COL0 + 2); bA = MFMA(w, fA0, z);  bB = MFMA(w, fB0, z);
        w = LW(F_COL0 + 3); bA = MFMA(w, fA1, bA); bB = MFMA(w, fB1, bB);
        half8 cK0a = packrelu(aA, bA), cK0b = packrelu(aB, bB);
        w = LW(F_COL0 + 4); aA = MFMA(w, fA0, z);  aB = MFMA(w, fB0, z);
        w = LW(F_COL0 + 5); aA = MFMA(w, fA1, aA); aB = MFMA(w, fB1, aB);
        w = LW(F_COL0 + 6); bA = MFMA(w, fA0, z);  bB = MFMA(w, fB0, z);
        w = LW(F_COL0 + 7); bA = MFMA(w, fA1, bA); bB = MFMA(w, fB1, bB);
        half8 cK1a = packrelu(aA, bA), cK1b = packrelu(aB, bB);
        SBAR();

        // ---- vis0: hv = relu([x|lenc|0] @ w_vis0), K=64 (rows 48+ zero) ----
        w = LW(F_VIS0 + 0); aA = MFMA(w, fA0, z);  aB = MFMA(w, fB0, z);
        w = LW(F_VIS0 + 1); aA = MFMA(w, fA1, aA); aB = MFMA(w, fB1, aB);
        w = LW(F_VIS0 + 2); bA = MFMA(w, fA0, z);  bB = MFMA(w, fB0, z);
        w = LW(F_VIS0 + 3); bA = MFMA(w, fA1, bA); bB = MFMA(w, fB1, bB);
        half8 vK0a = packrelu(aA, bA), vK0b = packrelu(aB, bB);
        w = LW(F_VIS0 + 4); aA = MFMA(w, fA0, z);  aB = MFMA(w, fB0, z);
        w = LW(F_VIS0 + 5); aA = MFMA(w, fA1, aA); aB = MFMA(w, fB1, aB);
        w = LW(F_VIS0 + 6); bA = MFMA(w, fA0, z);  bB = MFMA(w, fB0, z);
        w = LW(F_VIS0 + 7); bA = MFMA(w, fA1, bA); bB = MFMA(w, fB1, bB);
        half8 vK1a = packrelu(aA, bA), vK1b = packrelu(aB, bB);

        // ---- vis1 + sigmoid immediately (frees vK*, and fI* after this) ----
        f32x4 va = z, vb = z;
        w = LW(F_VIS1 + 0); va = MFMA(w, vK0a, va); vb = MFMA(w, vK0b, vb);
        w = LW(F_VIS1 + 1); va = MFMA(w, vK1a, va); vb = MFMA(w, vK1b, vb);
        float visA = 1.f / (1.f + expf(-va[0]));
        float visB = 1.f / (1.f + expf(-vb[0]));
        SBAR();

        // ---- col1: h2 = relu([hc|geo] @ w_col1), K=96 padded ----
        w = LW(F_COL1 + 0);  aA = MFMA(w, cK0a, z);  aB = MFMA(w, cK0b, z);
        w = LW(F_COL1 + 1);  aA = MFMA(w, cK1a, aA); aB = MFMA(w, cK1b, aB);
        w = LW(F_COL1 + 2);  aA = MFMA(w, gA,   aA); aB = MFMA(w, gB,   aB);
        w = LW(F_COL1 + 3);  bA = MFMA(w, cK0a, z);  bB = MFMA(w, cK0b, z);
        w = LW(F_COL1 + 4);  bA = MFMA(w, cK1a, bA); bB = MFMA(w, cK1b, bB);
        w = LW(F_COL1 + 5);  bA = MFMA(w, gA,   bA); bB = MFMA(w, gB,   bB);
        half8 h2K0a = packrelu(aA, bA), h2K0b = packrelu(aB, bB);
        w = LW(F_COL1 + 6);  aA = MFMA(w, cK0a, z);  aB = MFMA(w, cK0b, z);
        w = LW(F_COL1 + 7);  aA = MFMA(w, cK1a, aA); aB = MFMA(w, cK1b, aB);
        w = LW(F_COL1 + 8);  aA = MFMA(w, gA,   aA); aB = MFMA(w, gB,   aB);
        w = LW(F_COL1 + 9);  bA = MFMA(w, cK0a, z);  bB = MFMA(w, cK0b, z);
        w = LW(F_COL1 + 10); bA = MFMA(w, cK1a, bA); bB = MFMA(w, cK1b, bB);
        w = LW(F_COL1 + 11); bA = MFMA(w, gA,   bA); bB = MFMA(w, gB,   bB);
        half8 h2K1a = packrelu(aA, bA), h2K1b = packrelu(aB, bB);
        SBAR();

        // ---- col2: color = relu(h2 @ w_col2) * vis; rows 0..2 at q==0 ----
        f32x4 ca = z, cb = z;
        w = LW(F_COL2 + 0); ca = MFMA(w, h2K0a, ca); cb = MFMA(w, h2K0b, cb);
        w = LW(F_COL2 + 1); ca = MFMA(w, h2K1a, ca); cb = MFMA(w, h2K1b, cb);
        if (q == 0) {
            float* oa = out + (size_t)pt0 * 3;
            oa[0] = fmaxf(ca[0], 0.f) * visA;
            oa[1] = fmaxf(ca[1], 0.f) * visA;
            oa[2] = fmaxf(ca[2], 0.f) * visA;
            float* ob = out + (size_t)pt1 * 3;
            ob[0] = fmaxf(cb[0], 0.f) * visB;
            ob[1] = fmaxf(cb[1], 0.f) * visB;
            ob[2] = fmaxf(cb[2], 0.f) * visB;
        }
    }
    #undef LW
}

extern "C" void kernel_launch(void* const* d_in, const int* in_sizes, int n_in,
                              void* d_out, int out_size, void* d_ws, size_t ws_size,
                              hipStream_t stream) {
    const float* x_feat = (const float*)d_in[0];
    const float* dvec   = (const float*)d_in[1];
    const float* lvec   = (const float*)d_in[2];
    const float* w_sig0 = (const float*)d_in[3];
    const float* w_sig1 = (const float*)d_in[4];
    const float* w_col0 = (const float*)d_in[5];
    const float* w_col1 = (const float*)d_in[6];
    const float* w_col2 = (const float*)d_in[7];
    const float* w_vis0 = (const float*)d_in[8];
    const float* w_vis1 = (const float*)d_in[9];
    float* out = (float*)d_out;

    const int n = in_sizes[0] / 32;   // N points (1048576: multiple of 128)
    nerf_pf<<<GRID, BLOCK, 0, stream>>>(x_feat, dvec, lvec,
                                        w_sig0, w_sig1, w_col0, w_col1,
                                        w_col2, w_vis0, w_vis1, out, n);
}